// Round 3
// baseline (540.849 us; speedup 1.0000x reference)
//
#include <hip/hip_runtime.h>
#include <stdint.h>

#define B_   8
#define N_   256
#define D_   128
#define MID_ 128
#define FEAT_ 256

typedef __attribute__((ext_vector_type(4))) float  floatx4;
typedef __attribute__((ext_vector_type(8))) __bf16 bf16x8;

__device__ __forceinline__ floatx4 mfma16(bf16x8 a, bf16x8 b, floatx4 c) {
    return __builtin_amdgcn_mfma_f32_16x16x32_bf16(a, b, c, 0, 0, 0);
}

__device__ __forceinline__ bf16x8 cvt8(floatx4 a, floatx4 b) {
    bf16x8 r;
    r[0] = (__bf16)a[0]; r[1] = (__bf16)a[1]; r[2] = (__bf16)a[2]; r[3] = (__bf16)a[3];
    r[4] = (__bf16)b[0]; r[5] = (__bf16)b[1]; r[6] = (__bf16)b[2]; r[7] = (__bf16)b[3];
    return r;
}

// packed pair (k, k+1) of bf16 in one uint (k in low half)
__device__ __forceinline__ unsigned int pack2(float lo, float hi) {
    unsigned short u0 = __builtin_bit_cast(unsigned short, (__bf16)lo);
    unsigned short u1 = __builtin_bit_cast(unsigned short, (__bf16)hi);
    return (unsigned int)u0 | ((unsigned int)u1 << 16);
}

// swizzled fragment index for A-operand staging: [ks][mt][lane][jj]
__device__ __forceinline__ int widx(int k, int m) {
    return ((((k >> 5) * 8 + (m >> 4)) * 64 + ((k >> 3) & 3) * 16 + (m & 15)) << 3) + (k & 7);
}

// ---------------- kernel A: per-node GEMMs via MFMA (bf16) ----------------
// grid (32 row-tiles of 64, 3 weights). A = W^T (swizzled LDS), B = feat rows.
// wid 0: C = feat@W1 + (g@Wg + bg + b1 + be) ; wid 1: msg2 = feat@W2 + b2 ;
// wid 2: retA = feat@Wo1 + bo1 + bo2
__global__ void __launch_bounds__(256)
kA(const float* __restrict__ nfeat, const float* __restrict__ hidden,
   const float* __restrict__ W1, const float* __restrict__ W2,
   const float* __restrict__ Wo1,
   const float* __restrict__ g, const float* __restrict__ Wg,
   const float* __restrict__ bg, const float* __restrict__ b1,
   const float* __restrict__ be,
   const float* __restrict__ b2, const float* __restrict__ bo1,
   const float* __restrict__ bo2,
   float* __restrict__ C, float* __restrict__ msg2, float* __restrict__ retA) {
    __shared__ unsigned short Wb[8 * 8 * 64 * 8];   // 64 KB
    __shared__ float gplus_sh[MID_];
    int t = threadIdx.x;
    int wid = blockIdx.y;
    int bidx = blockIdx.x >> 2;                     // batch of this row-tile
    const float* W = (wid == 0) ? W1 : ((wid == 1) ? W2 : Wo1);
    // packed staging: per iter load rows k0,k0+1 (float4 along m), store 4 uints
#pragma unroll
    for (int it = 0; it < 16; ++it) {
        int id = t + it * 256;                      // 0..4095
        int m0 = (id & 31) * 4;
        int k0 = (id >> 5) * 2;
        floatx4 a = *(const floatx4*)&W[k0 * MID_ + m0];
        floatx4 bb = *(const floatx4*)&W[(k0 + 1) * MID_ + m0];
#pragma unroll
        for (int p = 0; p < 4; ++p)
            *(unsigned int*)&Wb[widx(k0, m0 + p)] = pack2(a[p], bb[p]);
    }
    if (wid == 0 && t < 128) {
        float acc = 0.f;
        for (int k = 0; k < D_; ++k)
            acc += g[bidx * D_ + k] * Wg[k * MID_ + t];
        gplus_sh[t] = acc + bg[t] + b1[t] + be[t];
    }
    __syncthreads();

    int lane = t & 63, w = t >> 6;
    int n16 = lane & 15, quad = lane >> 4;
    int R = blockIdx.x * 64 + w * 16 + n16;
    const float* frow0 = nfeat  + (size_t)R * D_ + quad * 8;
    const float* frow1 = hidden + (size_t)R * D_ + quad * 8;

    bf16x8 bfrag[8];
#pragma unroll
    for (int ks = 0; ks < 8; ++ks) {
        const float* p = (ks < 4) ? (frow0 + ks * 32) : (frow1 + (ks - 4) * 32);
        floatx4 v0 = *(const floatx4*)p;
        floatx4 v1 = *(const floatx4*)(p + 4);
        bfrag[ks] = cvt8(v0, v1);
    }

    float* outp = (wid == 0) ? C : ((wid == 1) ? msg2 : retA);
#pragma unroll 2
    for (int mt = 0; mt < 8; ++mt) {
        floatx4 acc = (floatx4)0.f;
#pragma unroll
        for (int ks = 0; ks < 8; ++ks) {
            bf16x8 a = *(const bf16x8*)&Wb[((ks * 8 + mt) * 64 + lane) << 3];
            acc = mfma16(a, bfrag[ks], acc);
        }
        int m0 = mt * 16 + quad * 4;
        floatx4 add;
        if (wid == 0)      add = *(const floatx4*)&gplus_sh[m0];
        else if (wid == 1) add = *(const floatx4*)&b2[m0];
        else {
            floatx4 x = *(const floatx4*)&bo1[m0];
            floatx4 y = *(const floatx4*)&bo2[m0];
            add = x + y;
        }
        *(floatx4*)&outp[(size_t)R * MID_ + m0] = acc + add;
    }
}

// ---------------- kernel B: fused msg_e GEMM + broadcast-add + mask-max + out ----------------
// one block per (b, j); wave w owns i in [w*64, w*64+64), pipelined 4 tiles of 16.
__global__ void __launch_bounds__(256, 3)
kB(const float* __restrict__ e, const float* __restrict__ We,
   const float* __restrict__ adj, const float* __restrict__ C,
   const float* __restrict__ msg2, const float* __restrict__ retA,
   const float* __restrict__ Wo2, float* __restrict__ out) {
    __shared__ unsigned short Wb[4 * 8 * 64 * 8];   // 32 KB
    __shared__ float adj_sh[N_];
    __shared__ float C_sh[MID_];
    __shared__ float wmax[4][MID_];
    __shared__ float msgs_sh[MID_];
    __shared__ float part[2][MID_];

    int t = threadIdx.x;
    int b = blockIdx.x >> 8, j = blockIdx.x & 255;

#pragma unroll
    for (int it = 0; it < 8; ++it) {
        int id = t + it * 256;                      // 0..2047
        int m0 = (id & 31) * 4;
        int k0 = (id >> 5) * 2;
        floatx4 a = *(const floatx4*)&We[k0 * MID_ + m0];
        floatx4 bb = *(const floatx4*)&We[(k0 + 1) * MID_ + m0];
#pragma unroll
        for (int p = 0; p < 4; ++p)
            *(unsigned int*)&Wb[widx(k0, m0 + p)] = pack2(a[p], bb[p]);
    }
    adj_sh[t] = adj[b * N_ * N_ + t * N_ + j];
    if (t < 128) C_sh[t] = C[(b * N_ + j) * MID_ + t];
    __syncthreads();

    int lane = t & 63, w = t >> 6;
    int n16 = lane & 15, quad = lane >> 4;
    const float* ebase = e + (size_t)b * N_ * N_ * D_ + (size_t)j * D_ + quad * 8;
    const float* m2b   = msg2 + (size_t)b * N_ * MID_;

    floatx4 rm[8];
#pragma unroll
    for (int mt = 0; mt < 8; ++mt) rm[mt] = (floatx4)(-INFINITY);

    floatx4 raw[8];
    floatx4 m2v[8];
    bf16x8  ef[4];

    // preload tile 0 e-rows
    {
        const float* rp = ebase + (size_t)(w * 64 + n16) * (N_ * D_);
#pragma unroll
        for (int ks = 0; ks < 4; ++ks) {
            raw[2 * ks]     = *(const floatx4*)(rp + ks * 32);
            raw[2 * ks + 1] = *(const floatx4*)(rp + ks * 32 + 4);
        }
    }

#pragma unroll
    for (int t_ = 0; t_ < 4; ++t_) {
        int i = w * 64 + t_ * 16 + n16;
        // convert current tile (frees raw)
#pragma unroll
        for (int ks = 0; ks < 4; ++ks) ef[ks] = cvt8(raw[2 * ks], raw[2 * ks + 1]);
        // prefetch next tile e-rows (full-tile latency cover)
        if (t_ < 3) {
            const float* rp = ebase + (size_t)(i + 16) * (N_ * D_);
#pragma unroll
            for (int ks = 0; ks < 4; ++ks) {
                raw[2 * ks]     = *(const floatx4*)(rp + ks * 32);
                raw[2 * ks + 1] = *(const floatx4*)(rp + ks * 32 + 4);
            }
        }
        // hoist this tile's msg2 row segments ahead of the MFMA stretch
        {
            const float* mp = m2b + (size_t)i * MID_;
#pragma unroll
            for (int mt = 0; mt < 8; ++mt)
                m2v[mt] = *(const floatx4*)&mp[mt * 16 + quad * 4];
        }
        float adjc = adj_sh[i];

#pragma unroll
        for (int mtp = 0; mtp < 4; ++mtp) {
            floatx4 a0 = (floatx4)0.f, a1 = (floatx4)0.f;
#pragma unroll
            for (int ks = 0; ks < 4; ++ks) {
                bf16x8 aW0 = *(const bf16x8*)&Wb[((ks * 8 + 2 * mtp) * 64 + lane) << 3];
                bf16x8 aW1 = *(const bf16x8*)&Wb[((ks * 8 + 2 * mtp + 1) * 64 + lane) << 3];
                a0 = mfma16(aW0, ef[ks], a0);
                a1 = mfma16(aW1, ef[ks], a1);
            }
            int m0 = (2 * mtp) * 16 + quad * 4;
            floatx4 c0 = *(const floatx4*)&C_sh[m0];
            floatx4 c1 = *(const floatx4*)&C_sh[m0 + 16];
#pragma unroll
            for (int r = 0; r < 4; ++r) {
                float v0 = (a0[r] + c0[r] + m2v[2 * mtp][r]) * adjc;
                float v1 = (a1[r] + c1[r] + m2v[2 * mtp + 1][r]) * adjc;
                rm[2 * mtp][r]     = fmaxf(rm[2 * mtp][r], v0);
                rm[2 * mtp + 1][r] = fmaxf(rm[2 * mtp + 1][r], v1);
            }
        }
    }

    // reduce over i (n16 lanes) via xor-shuffles, stash per-wave result
#pragma unroll
    for (int mt = 0; mt < 8; ++mt) {
#pragma unroll
        for (int r = 0; r < 4; ++r) {
            float v = rm[mt][r];
            v = fmaxf(v, __shfl_xor(v, 1, 64));
            v = fmaxf(v, __shfl_xor(v, 2, 64));
            v = fmaxf(v, __shfl_xor(v, 4, 64));
            v = fmaxf(v, __shfl_xor(v, 8, 64));
            rm[mt][r] = v;
        }
    }
    if (n16 == 0) {
#pragma unroll
        for (int mt = 0; mt < 8; ++mt)
            *(floatx4*)&wmax[w][mt * 16 + quad * 4] = rm[mt];
    }
    __syncthreads();

    int m = t & 127, h = t >> 7;
    if (t < 128) {
        float mx = fmaxf(fmaxf(wmax[0][m], wmax[1][m]), fmaxf(wmax[2][m], wmax[3][m]));
        msgs_sh[m] = mx;
    }
    __syncthreads();

    // fused: ret = retA + msgs @ Wo2 (split-k over thread halves)
    float a2 = 0.f;
    for (int k = h * 64; k < h * 64 + 64; ++k)
        a2 += msgs_sh[k] * Wo2[k * MID_ + m];
    part[h][m] = a2;
    __syncthreads();
    if (t < 128) {
        int R = b * N_ + j;
        out[(size_t)R * MID_ + m] = retA[R * MID_ + m] + part[0][m] + part[1][m];
    }
}

extern "C" void kernel_launch(void* const* d_in, const int* in_sizes, int n_in,
                              void* d_out, int out_size, void* d_ws, size_t ws_size,
                              hipStream_t stream) {
    (void)in_sizes; (void)n_in; (void)out_size; (void)ws_size;
    const float* hidden = (const float*)d_in[0];
    const float* nfeat  = (const float*)d_in[1];
    const float* e      = (const float*)d_in[2];
    const float* g      = (const float*)d_in[3];
    const float* adj    = (const float*)d_in[4];
    const float* W1  = (const float*)d_in[5];
    const float* b1  = (const float*)d_in[6];
    const float* W2  = (const float*)d_in[7];
    const float* b2  = (const float*)d_in[8];
    const float* We  = (const float*)d_in[9];
    const float* be  = (const float*)d_in[10];
    const float* Wg  = (const float*)d_in[11];
    const float* bg  = (const float*)d_in[12];
    const float* Wo1 = (const float*)d_in[13];
    const float* bo1 = (const float*)d_in[14];
    const float* Wo2 = (const float*)d_in[15];
    const float* bo2 = (const float*)d_in[16];
    float* outp = (float*)d_out;

    float* ws   = (float*)d_ws;
    float* C    = ws;                        // 262144
    float* msg2 = C + 262144;                // 262144
    float* retA = msg2 + 262144;             // 262144

    kA<<<dim3(32, 3), 256, 0, stream>>>(nfeat, hidden, W1, W2, Wo1,
                                        g, Wg, bg, b1, be, b2, bo1, bo2,
                                        C, msg2, retA);
    kB<<<2048, 256, 0, stream>>>(e, We, adj, C, msg2, retA, Wo2, outp);
}